// Round 2
// baseline (2568.544 us; speedup 1.0000x reference)
//
#include <hip/hip_runtime.h>

#define N 32768
#define F 768
#define C 64
#define P 8192
#define TAU 1e-3f

typedef __attribute__((ext_vector_type(8))) short short8;
typedef __attribute__((ext_vector_type(4))) float f32x4;

// ---------------- workspace layout (float offsets) ----------------
#define WS_CNT    0                        // cnT   fp32 [C][P] k-major (gather+recheck)
#define WS_CC     (WS_CNT + C*P)           // cc    [P]
#define WS_ZQT    (WS_CC + P)              // zqT   fp32 [C][N] k-major (loss+recheck)
#define WS_CODEST (WS_ZQT + C*N)           // codesT[C][N]
#define WS_IDX    (WS_CODEST + C*N)        // idx   [N] int
#define WS_QN     (WS_IDX + N)             // queue count (int)
#define WS_ACC    (WS_QN + 1)              // loss accumulator
#define WS_QLIST  (WS_ACC + 1)             // queue [N] int
#define WS_CNH    ((WS_QLIST + N + 3) & ~3)  // cn_hi bf16 [P][C] row-major
#define WS_CNL    (WS_CNH + (C*P)/2)       // cn_lo bf16 [P][C]
#define WS_ZQH    (WS_CNL + (C*P)/2)       // zq_hi bf16 [N][C] row-major
#define WS_ZQL    (WS_ZQH + (C*N)/2)       // zq_lo bf16 [N][C]
// end = WS_ZQL + (C*N)/2 ≈ 7.41M floats ≈ 29.7 MB

#define OUT_LOSS_OFF (N*F)
#define OUT_IDX_OFF  (N*F + 1)

__device__ inline unsigned short f2bf(float x) {   // fp32 -> bf16 RNE
    union { float f; unsigned u; } v; v.f = x;
    unsigned r = v.u + 0x7fffu + ((v.u >> 16) & 1u);
    return (unsigned short)(r >> 16);
}
__device__ inline float bf2f(unsigned short b) {
    union { unsigned u; float f; } v; v.u = ((unsigned)b) << 16;
    return v.f;
}

// ---------------- K1: normalize codebook -> cnT [C][P], cc, cn_hi/lo [P][C] ----
__global__ __launch_bounds__(256) void k1_norm_codebook(
    const float* __restrict__ cb, float* __restrict__ cnT, float* __restrict__ cc,
    unsigned short* __restrict__ cnh, unsigned short* __restrict__ cnl) {
    int p = blockIdx.x * 256 + threadIdx.x;   // one thread per page
    const float4* cb4 = (const float4*)(cb + (size_t)p * C);
    float4 v[16];
    float ss = 0.f;
#pragma unroll
    for (int i = 0; i < 16; ++i) {
        v[i] = cb4[i];
        ss += v[i].x * v[i].x + v[i].y * v[i].y + v[i].z * v[i].z + v[i].w * v[i].w;
    }
    float nrm = sqrtf(ss);
    float s2 = 0.f;
    unsigned short hb[64], lb[64];
#pragma unroll
    for (int i = 0; i < 16; ++i) {
        float c4[4] = {v[i].x / nrm, v[i].y / nrm, v[i].z / nrm, v[i].w / nrm};
#pragma unroll
        for (int j = 0; j < 4; ++j) {
            cnT[(size_t)(i * 4 + j) * P + p] = c4[j];
            s2 += c4[j] * c4[j];
            unsigned short h = f2bf(c4[j]);
            hb[i * 4 + j] = h;
            lb[i * 4 + j] = f2bf(c4[j] - bf2f(h));
        }
    }
    cc[p] = s2;
#pragma unroll
    for (int i = 0; i < 8; ++i) {
        uint4 hv, lv;
        hv.x = (unsigned)hb[i*8+0] | ((unsigned)hb[i*8+1] << 16);
        hv.y = (unsigned)hb[i*8+2] | ((unsigned)hb[i*8+3] << 16);
        hv.z = (unsigned)hb[i*8+4] | ((unsigned)hb[i*8+5] << 16);
        hv.w = (unsigned)hb[i*8+6] | ((unsigned)hb[i*8+7] << 16);
        lv.x = (unsigned)lb[i*8+0] | ((unsigned)lb[i*8+1] << 16);
        lv.y = (unsigned)lb[i*8+2] | ((unsigned)lb[i*8+3] << 16);
        lv.z = (unsigned)lb[i*8+4] | ((unsigned)lb[i*8+5] << 16);
        lv.w = (unsigned)lb[i*8+6] | ((unsigned)lb[i*8+7] << 16);
        *(uint4*)&cnh[(size_t)p * 64 + i * 8] = hv;
        *(uint4*)&cnl[(size_t)p * 64 + i * 8] = lv;
    }
}

// ---------------- K2: zq = normalize(z @ w_in^T + b_in) -> zqT, zq_hi/lo ----
__global__ __launch_bounds__(256) void k2_project(
    const float* __restrict__ z, const float* __restrict__ w_in, const float* __restrict__ b_in,
    float* __restrict__ zqT, unsigned short* __restrict__ zqh, unsigned short* __restrict__ zql) {
    __shared__ float zrow[128 * 33];
    __shared__ float wrow[64 * 32];
    __shared__ float red[128 * 9];
    int tid = threadIdx.x;
    int tr = tid & 31;        // row group: 4 rows each -> 128 rows
    int tc = tid >> 5;        // code group: 8 codes each -> 64 codes
    int rb = blockIdx.x * 128;

    float y[4][8];
#pragma unroll
    for (int i = 0; i < 4; ++i)
#pragma unroll
        for (int j = 0; j < 8; ++j) y[i][j] = 0.f;

    for (int kt = 0; kt < F; kt += 32) {
        __syncthreads();
        for (int i = tid; i < 128 * 32; i += 256) {
            int r = i >> 5, k = i & 31;
            zrow[r * 33 + k] = z[(size_t)(rb + r) * F + kt + k];
        }
        for (int i = tid; i < 64 * 32; i += 256) {
            int c = i >> 5, k = i & 31;
            wrow[c * 32 + k] = w_in[(size_t)c * F + kt + k];
        }
        __syncthreads();
#pragma unroll
        for (int k4 = 0; k4 < 8; ++k4) {
            float zs[4][4];
#pragma unroll
            for (int i = 0; i < 4; ++i)
#pragma unroll
                for (int kk = 0; kk < 4; ++kk)
                    zs[i][kk] = zrow[(tr * 4 + i) * 33 + k4 * 4 + kk];
#pragma unroll
            for (int j = 0; j < 8; ++j) {
                float4 wv = *(const float4*)&wrow[(tc * 8 + j) * 32 + k4 * 4];
#pragma unroll
                for (int i = 0; i < 4; ++i)
                    y[i][j] = fmaf(zs[i][3], wv.w,
                              fmaf(zs[i][2], wv.z,
                              fmaf(zs[i][1], wv.y,
                              fmaf(zs[i][0], wv.x, y[i][j]))));
            }
        }
    }
#pragma unroll
    for (int j = 0; j < 8; ++j) {
        float b = b_in[tc * 8 + j];
#pragma unroll
        for (int i = 0; i < 4; ++i) y[i][j] += b;
    }
    __syncthreads();
#pragma unroll
    for (int i = 0; i < 4; ++i) {
        float s = 0.f;
#pragma unroll
        for (int j = 0; j < 8; ++j) s += y[i][j] * y[i][j];
        red[(tr * 4 + i) * 9 + tc] = s;
    }
    __syncthreads();
    float nrm[4];
#pragma unroll
    for (int i = 0; i < 4; ++i) {
        float t = 0.f;
#pragma unroll
        for (int t8 = 0; t8 < 8; ++t8) t += red[(tr * 4 + i) * 9 + t8];
        nrm[i] = sqrtf(t);
    }
    float q[4][8];
#pragma unroll
    for (int i = 0; i < 4; ++i)
#pragma unroll
        for (int j = 0; j < 8; ++j) q[i][j] = y[i][j] / nrm[i];
    // store transposed fp32: zqT[c][rb + tr*4 .. +3]
#pragma unroll
    for (int j = 0; j < 8; ++j) {
        int c = tc * 8 + j;
        float4 o = make_float4(q[0][j], q[1][j], q[2][j], q[3][j]);
        *(float4*)&zqT[(size_t)c * N + rb + tr * 4] = o;
    }
    // store row-major bf16 hi/lo: zqh/zql[row][64]
#pragma unroll
    for (int i = 0; i < 4; ++i) {
        unsigned short h[8], l[8];
#pragma unroll
        for (int j = 0; j < 8; ++j) {
            h[j] = f2bf(q[i][j]);
            l[j] = f2bf(q[i][j] - bf2f(h[j]));
        }
        uint4 hv, lv;
        hv.x = (unsigned)h[0] | ((unsigned)h[1] << 16);
        hv.y = (unsigned)h[2] | ((unsigned)h[3] << 16);
        hv.z = (unsigned)h[4] | ((unsigned)h[5] << 16);
        hv.w = (unsigned)h[6] | ((unsigned)h[7] << 16);
        lv.x = (unsigned)l[0] | ((unsigned)l[1] << 16);
        lv.y = (unsigned)l[2] | ((unsigned)l[3] << 16);
        lv.z = (unsigned)l[4] | ((unsigned)l[5] << 16);
        lv.w = (unsigned)l[6] | ((unsigned)l[7] << 16);
        size_t ro = (size_t)(rb + tr * 4 + i) * 64 + tc * 8;
        *(uint4*)&zqh[ro] = hv;
        *(uint4*)&zql[ro] = lv;
    }
}

// ---------------- K3: split-bf16 MFMA distance + top-2 argmin ----------------
// block = 256 thr = 4 waves; block covers 128 rows (wave: 32 rows = 2 m-tiles of 16)
// page loop: tiles of 128 pages (8 n-tiles of 16); K=64 = 2 k-frags of 32
__global__ __launch_bounds__(256) void k3_argmin_mfma(
    const unsigned short* __restrict__ zqh, const unsigned short* __restrict__ zql,
    const unsigned short* __restrict__ cnh, const unsigned short* __restrict__ cnl,
    const float* __restrict__ cc,
    int* __restrict__ idx_ws, float* __restrict__ idx_out,
    int* __restrict__ qn, int* __restrict__ qlist) {
    __shared__ unsigned short lfrag[8 * 4 * 64 * 8];   // [nt][f][lane][8] = 32 KB
    __shared__ float lcc[128];
    int tid = threadIdx.x;
    int w = tid >> 6, lane = tid & 63;
    int col = lane & 15, quad = lane >> 4;
    int rb = blockIdx.x * 128;
    int wrow = rb + w * 32;

    // A-frags (direct from global, once): A[m=lane&15][k=quad*8+j]
    short8 ah[2][2], al[2][2];
#pragma unroll
    for (int mt = 0; mt < 2; ++mt)
#pragma unroll
        for (int kf = 0; kf < 2; ++kf) {
            size_t off = (size_t)(wrow + mt * 16 + col) * 64 + kf * 32 + quad * 8;
            ah[mt][kf] = *(const short8*)&zqh[off];
            al[mt][kf] = *(const short8*)&zql[off];
        }

    float d1[8], d2[8]; int i1[8], i2[8];
#pragma unroll
    for (int s = 0; s < 8; ++s) { d1[s] = 3.4e38f; d2[s] = 3.4e38f; i1[s] = 0; i2[s] = 0; }

    // staging role: quad-chunk fastest for 64B-contiguous global reads
    int sq = tid & 3, scol = (tid >> 2) & 15, sf = tid >> 6;   // sf: 0=hi k0,1=hi k1,2=lo k0,3=lo k1
    const unsigned short* ssrc = (sf & 2) ? cnl : cnh;
    int skf = sf & 1;

    for (int pt = 0; pt < P; pt += 128) {
        __syncthreads();
#pragma unroll
        for (int nt = 0; nt < 8; ++nt) {
            int p = pt + nt * 16 + scol;
            uint4 dv = *(const uint4*)&ssrc[(size_t)p * 64 + skf * 32 + sq * 8];
            *(uint4*)&lfrag[(((nt * 4 + sf) * 64) + sq * 16 + scol) * 8] = dv;
        }
        if (tid < 128) lcc[tid] = cc[pt + tid];
        __syncthreads();
#pragma unroll 2
        for (int nt = 0; nt < 8; ++nt) {
            short8 bh0 = *(const short8*)&lfrag[((nt * 4 + 0) * 64 + lane) * 8];
            short8 bh1 = *(const short8*)&lfrag[((nt * 4 + 1) * 64 + lane) * 8];
            short8 bl0 = *(const short8*)&lfrag[((nt * 4 + 2) * 64 + lane) * 8];
            short8 bl1 = *(const short8*)&lfrag[((nt * 4 + 3) * 64 + lane) * 8];
            float ccv = lcc[nt * 16 + col];
            int p = pt + nt * 16 + col;
#pragma unroll
            for (int mt = 0; mt < 2; ++mt) {
                f32x4 acc = {0.f, 0.f, 0.f, 0.f};
                acc = __builtin_amdgcn_mfma_f32_16x16x32_bf16(ah[mt][0], bh0, acc, 0, 0, 0);
                acc = __builtin_amdgcn_mfma_f32_16x16x32_bf16(ah[mt][1], bh1, acc, 0, 0, 0);
                acc = __builtin_amdgcn_mfma_f32_16x16x32_bf16(ah[mt][0], bl0, acc, 0, 0, 0);
                acc = __builtin_amdgcn_mfma_f32_16x16x32_bf16(ah[mt][1], bl1, acc, 0, 0, 0);
                acc = __builtin_amdgcn_mfma_f32_16x16x32_bf16(al[mt][0], bh0, acc, 0, 0, 0);
                acc = __builtin_amdgcn_mfma_f32_16x16x32_bf16(al[mt][1], bh1, acc, 0, 0, 0);
#pragma unroll
                for (int r = 0; r < 4; ++r) {
                    float d = fmaf(acc[r], -2.0f, ccv);   // ssq row-const: dropped (argmin invariant)
                    int s = mt * 4 + r;
                    bool lt1 = d < d1[s];
                    bool lt2 = d < d2[s];
                    float nd2 = lt1 ? d1[s] : (lt2 ? d : d2[s]);
                    int   ni2 = lt1 ? i1[s] : (lt2 ? p : i2[s]);
                    d1[s] = lt1 ? d : d1[s];
                    i1[s] = lt1 ? p : i1[s];
                    d2[s] = nd2; i2[s] = ni2;
                }
            }
        }
    }
    // merge top-2 across the 16 cols sharing each row (xor 1,2,4,8 stays in-quad)
#pragma unroll
    for (int s = 0; s < 8; ++s) {
        float a1 = d1[s], a2 = d2[s]; int ai1 = i1[s], ai2 = i2[s];
#pragma unroll
        for (int m = 1; m <= 8; m <<= 1) {
            float b1 = __shfl_xor(a1, m); int bi1 = __shfl_xor(ai1, m);
            float b2 = __shfl_xor(a2, m); int bi2 = __shfl_xor(ai2, m);
            bool bw = (b1 < a1) || (b1 == a1 && bi1 < ai1);
            float w1 = bw ? b1 : a1; int wi1 = bw ? bi1 : ai1;
            float l1 = bw ? a1 : b1; int li1 = bw ? ai1 : bi1;
            float w2 = l1; int wi2 = li1;
            if (a2 < w2 || (a2 == w2 && ai2 < wi2)) { w2 = a2; wi2 = ai2; }
            if (b2 < w2 || (b2 == w2 && bi2 < wi2)) { w2 = b2; wi2 = bi2; }
            a1 = w1; ai1 = wi1; a2 = w2; ai2 = wi2;
        }
        if (col == 0) {
            int row = wrow + (s >> 2) * 16 + quad * 4 + (s & 3);
            idx_ws[row] = ai1;
            idx_out[row] = (float)ai1;
            if (a2 - a1 < TAU) {            // near-tie: exact fp32 recheck
                int qi = atomicAdd(qn, 1);
                qlist[qi] = row;
            }
        }
    }
}

// ---------------- K3r: exact fp32 full-row argmin for flagged rows ----------------
__global__ __launch_bounds__(256) void k3_recheck(
    const float* __restrict__ zqT, const float* __restrict__ cnT,
    const float* __restrict__ cc, const int* __restrict__ qn,
    const int* __restrict__ qlist, int* __restrict__ idx_ws, float* __restrict__ idx_out) {
    int nq = qn[0];
    int wid = blockIdx.x * 4 + (threadIdx.x >> 6);
    int lane = threadIdx.x & 63;
    for (int e = wid; e < nq; e += 256 * 4) {
        int row = qlist[e];
        float zr[64];
#pragma unroll
        for (int k = 0; k < 64; ++k) zr[k] = zqT[(size_t)k * N + row];
        float best = 3.4e38f; int bi = 0;
        for (int pb = 0; pb < P; pb += 64) {
            int p = pb + lane;
            float acc = 0.f;
#pragma unroll
            for (int k = 0; k < 64; ++k) acc = fmaf(zr[k], cnT[(size_t)k * P + p], acc);
            float d = fmaf(acc, -2.0f, cc[p]);
            if (d < best) { best = d; bi = p; }   // per-lane pages ascending: strict < keeps first
        }
#pragma unroll
        for (int m = 1; m < 64; m <<= 1) {
            float ob = __shfl_xor(best, m); int oi = __shfl_xor(bi, m);
            if (ob < best || (ob == best && oi < bi)) { best = ob; bi = oi; }
        }
        if (lane == 0) { idx_ws[row] = bi; idx_out[row] = (float)bi; }
    }
}

// ---------------- K3b: gather codesT[k][r] = cnT[k][idx[r]] ----------------
__global__ __launch_bounds__(256) void k3b_gather(
    const float* __restrict__ cnT, const int* __restrict__ idx, float* __restrict__ codesT) {
    for (size_t i = (size_t)blockIdx.x * 256 + threadIdx.x; i < (size_t)C * N;
         i += (size_t)gridDim.x * 256) {
        int k = (int)(i >> 15);          // N = 2^15
        int r = (int)(i & (N - 1));
        codesT[i] = cnT[(size_t)k * P + idx[r]];
    }
}

// ---------------- K4: out = codes @ w_out^T + b_out ----------------
__global__ __launch_bounds__(256) void k4_out(
    const float* __restrict__ codesT, const float* __restrict__ w_out,
    const float* __restrict__ b_out, float* __restrict__ out) {
    __shared__ float cds[64 * 64];
    __shared__ float wo[64 * 65];
    int tid = threadIdx.x;
    int tx = tid & 15;
    int ty = tid >> 4;
    int rb = blockIdx.x * 64;

    for (int i = tid; i < 64 * 64; i += 256) {
        int k = i >> 6, r = i & 63;
        cds[k * 64 + r] = codesT[(size_t)k * N + rb + r];
    }
    for (int ft = 0; ft < F; ft += 64) {
        __syncthreads();
        for (int i = tid; i < 64 * 64; i += 256) {
            int k = i & 63, f = i >> 6;
            wo[k * 65 + f] = w_out[(size_t)(ft + f) * C + k];
        }
        __syncthreads();
        float acc[4][4];
#pragma unroll
        for (int i = 0; i < 4; ++i)
#pragma unroll
            for (int j = 0; j < 4; ++j) acc[i][j] = 0.f;
#pragma unroll 8
        for (int k = 0; k < 64; ++k) {
            float4 cf = *(const float4*)&cds[k * 64 + ty * 4];
            float cr[4] = {cf.x, cf.y, cf.z, cf.w};
            float wv[4];
#pragma unroll
            for (int j = 0; j < 4; ++j) wv[j] = wo[k * 65 + tx * 4 + j];
#pragma unroll
            for (int i = 0; i < 4; ++i)
#pragma unroll
                for (int j = 0; j < 4; ++j)
                    acc[i][j] = fmaf(cr[i], wv[j], acc[i][j]);
        }
#pragma unroll
        for (int i = 0; i < 4; ++i) {
            int r = rb + ty * 4 + i;
            float4 o;
            o.x = acc[i][0] + b_out[ft + tx * 4 + 0];
            o.y = acc[i][1] + b_out[ft + tx * 4 + 1];
            o.z = acc[i][2] + b_out[ft + tx * 4 + 2];
            o.w = acc[i][3] + b_out[ft + tx * 4 + 3];
            *(float4*)&out[(size_t)r * F + ft + tx * 4] = o;
        }
    }
}

// ---------------- K5: loss partial sums ----------------
__global__ __launch_bounds__(256) void k5_loss(
    const float* __restrict__ zqT, const float* __restrict__ codesT, float* __restrict__ acc) {
    float s = 0.f;
    for (size_t i = (size_t)blockIdx.x * 256 + threadIdx.x; i < (size_t)C * N;
         i += (size_t)gridDim.x * 256) {
        float d = zqT[i] - codesT[i];
        s = fmaf(d, d, s);
    }
#pragma unroll
    for (int off = 32; off > 0; off >>= 1) s += __shfl_xor(s, off);
    __shared__ float wsum[4];
    int lane = threadIdx.x & 63, wv = threadIdx.x >> 6;
    if (lane == 0) wsum[wv] = s;
    __syncthreads();
    if (threadIdx.x == 0) atomicAdd(acc, wsum[0] + wsum[1] + wsum[2] + wsum[3]);
}

// ---------------- K6: finalize loss ----------------
__global__ void k6_finalize(const float* __restrict__ acc, float* __restrict__ loss_out) {
    float m = acc[0] / (float)(C * N);
    loss_out[0] = 0.25f * m + m;   // BETA*mean + mean
}

extern "C" void kernel_launch(void* const* d_in, const int* in_sizes, int n_in,
                              void* d_out, int out_size, void* d_ws, size_t ws_size,
                              hipStream_t stream) {
    const float* z      = (const float*)d_in[0];
    const float* w_in   = (const float*)d_in[1];
    const float* b_in   = (const float*)d_in[2];
    const float* w_out  = (const float*)d_in[3];
    const float* b_out  = (const float*)d_in[4];
    const float* cb     = (const float*)d_in[5];
    float* out = (float*)d_out;
    float* ws  = (float*)d_ws;

    unsigned short* cnh = (unsigned short*)(ws + WS_CNH);
    unsigned short* cnl = (unsigned short*)(ws + WS_CNL);
    unsigned short* zqh = (unsigned short*)(ws + WS_ZQH);
    unsigned short* zql = (unsigned short*)(ws + WS_ZQL);

    hipMemsetAsync(ws + WS_QN, 0, 2 * sizeof(float), stream);   // qn + loss acc
    k1_norm_codebook<<<P / 256, 256, 0, stream>>>(cb, ws + WS_CNT, ws + WS_CC, cnh, cnl);
    k2_project<<<N / 128, 256, 0, stream>>>(z, w_in, b_in, ws + WS_ZQT, zqh, zql);
    k3_argmin_mfma<<<N / 128, 256, 0, stream>>>(zqh, zql, cnh, cnl, ws + WS_CC,
                                                (int*)(ws + WS_IDX), out + OUT_IDX_OFF,
                                                (int*)(ws + WS_QN), (int*)(ws + WS_QLIST));
    k3_recheck<<<256, 256, 0, stream>>>(ws + WS_ZQT, ws + WS_CNT, ws + WS_CC,
                                        (const int*)(ws + WS_QN), (const int*)(ws + WS_QLIST),
                                        (int*)(ws + WS_IDX), out + OUT_IDX_OFF);
    k3b_gather<<<2048, 256, 0, stream>>>(ws + WS_CNT, (const int*)(ws + WS_IDX), ws + WS_CODEST);
    k4_out<<<N / 64, 256, 0, stream>>>(ws + WS_CODEST, w_out, b_out, out);
    k5_loss<<<2048, 256, 0, stream>>>(ws + WS_ZQT, ws + WS_CODEST, ws + WS_ACC);
    k6_finalize<<<1, 1, 0, stream>>>(ws + WS_ACC, out + OUT_LOSS_OFF);
}

// Round 3
// 715.624 us; speedup vs baseline: 3.5892x; 3.5892x over previous
//
#include <hip/hip_runtime.h>

#define N 32768
#define F 768
#define C 64
#define P 8192
#define TAU 1e-3f

typedef __attribute__((ext_vector_type(8))) short short8;
typedef __attribute__((ext_vector_type(4))) float f32x4;

// ---------------- workspace layout (float offsets) ----------------
#define WS_CNT    0                        // cnT   fp32 [C][P] k-major (gather+recheck)
#define WS_CC     (WS_CNT + C*P)           // cc    [P]
#define WS_ZQT    (WS_CC + P)              // zqT   fp32 [C][N] k-major (loss+recheck)
#define WS_CODEST (WS_ZQT + C*N)           // codesT[C][N]
#define WS_IDX    (WS_CODEST + C*N)        // idx   [N] int
#define WS_QN     (WS_IDX + N)             // queue count (int)
#define WS_ACC    (WS_QN + 1)              // loss accumulator
#define WS_QLIST  (WS_ACC + 1)             // queue [N] int
#define WS_CNH    ((WS_QLIST + N + 3) & ~3)  // cn_hi bf16 [P][C] row-major
#define WS_CNL    (WS_CNH + (C*P)/2)       // cn_lo bf16 [P][C]
#define WS_ZQH    (WS_CNL + (C*P)/2)       // zq_hi bf16 [N][C] row-major
#define WS_ZQL    (WS_ZQH + (C*N)/2)       // zq_lo bf16 [N][C]
// end = WS_ZQL + (C*N)/2 ≈ 7.41M floats ≈ 29.7 MB

#define OUT_LOSS_OFF (N*F)
#define OUT_IDX_OFF  (N*F + 1)

__device__ inline unsigned short f2bf(float x) {   // fp32 -> bf16 RNE
    union { float f; unsigned u; } v; v.f = x;
    unsigned r = v.u + 0x7fffu + ((v.u >> 16) & 1u);
    return (unsigned short)(r >> 16);
}
__device__ inline float bf2f(unsigned short b) {
    union { unsigned u; float f; } v; v.u = ((unsigned)b) << 16;
    return v.f;
}

// ---------------- K1: normalize codebook -> cnT [C][P], cc, cn_hi/lo [P][C] ----
__global__ __launch_bounds__(256) void k1_norm_codebook(
    const float* __restrict__ cb, float* __restrict__ cnT, float* __restrict__ cc,
    unsigned short* __restrict__ cnh, unsigned short* __restrict__ cnl) {
    int p = blockIdx.x * 256 + threadIdx.x;   // one thread per page
    const float4* cb4 = (const float4*)(cb + (size_t)p * C);
    float4 v[16];
    float ss = 0.f;
#pragma unroll
    for (int i = 0; i < 16; ++i) {
        v[i] = cb4[i];
        ss += v[i].x * v[i].x + v[i].y * v[i].y + v[i].z * v[i].z + v[i].w * v[i].w;
    }
    float nrm = sqrtf(ss);
    float s2 = 0.f;
    unsigned short hb[64], lb[64];
#pragma unroll
    for (int i = 0; i < 16; ++i) {
        float c4[4] = {v[i].x / nrm, v[i].y / nrm, v[i].z / nrm, v[i].w / nrm};
#pragma unroll
        for (int j = 0; j < 4; ++j) {
            cnT[(size_t)(i * 4 + j) * P + p] = c4[j];
            s2 += c4[j] * c4[j];
            unsigned short h = f2bf(c4[j]);
            hb[i * 4 + j] = h;
            lb[i * 4 + j] = f2bf(c4[j] - bf2f(h));
        }
    }
    cc[p] = s2;
#pragma unroll
    for (int i = 0; i < 8; ++i) {
        uint4 hv, lv;
        hv.x = (unsigned)hb[i*8+0] | ((unsigned)hb[i*8+1] << 16);
        hv.y = (unsigned)hb[i*8+2] | ((unsigned)hb[i*8+3] << 16);
        hv.z = (unsigned)hb[i*8+4] | ((unsigned)hb[i*8+5] << 16);
        hv.w = (unsigned)hb[i*8+6] | ((unsigned)hb[i*8+7] << 16);
        lv.x = (unsigned)lb[i*8+0] | ((unsigned)lb[i*8+1] << 16);
        lv.y = (unsigned)lb[i*8+2] | ((unsigned)lb[i*8+3] << 16);
        lv.z = (unsigned)lb[i*8+4] | ((unsigned)lb[i*8+5] << 16);
        lv.w = (unsigned)lb[i*8+6] | ((unsigned)lb[i*8+7] << 16);
        *(uint4*)&cnh[(size_t)p * 64 + i * 8] = hv;
        *(uint4*)&cnl[(size_t)p * 64 + i * 8] = lv;
    }
}

// ---------------- K2: zq = normalize(z @ w_in^T + b_in) -> zqT, zq_hi/lo ----
__global__ __launch_bounds__(256) void k2_project(
    const float* __restrict__ z, const float* __restrict__ w_in, const float* __restrict__ b_in,
    float* __restrict__ zqT, unsigned short* __restrict__ zqh, unsigned short* __restrict__ zql) {
    __shared__ float zrow[128 * 33];
    __shared__ float wrow[64 * 32];
    __shared__ float red[128 * 9];
    int tid = threadIdx.x;
    int tr = tid & 31;        // row group: 4 rows each -> 128 rows
    int tc = tid >> 5;        // code group: 8 codes each -> 64 codes
    int rb = blockIdx.x * 128;

    float y[4][8];
#pragma unroll
    for (int i = 0; i < 4; ++i)
#pragma unroll
        for (int j = 0; j < 8; ++j) y[i][j] = 0.f;

    for (int kt = 0; kt < F; kt += 32) {
        __syncthreads();
        for (int i = tid; i < 128 * 32; i += 256) {
            int r = i >> 5, k = i & 31;
            zrow[r * 33 + k] = z[(size_t)(rb + r) * F + kt + k];
        }
        for (int i = tid; i < 64 * 32; i += 256) {
            int c = i >> 5, k = i & 31;
            wrow[c * 32 + k] = w_in[(size_t)c * F + kt + k];
        }
        __syncthreads();
#pragma unroll
        for (int k4 = 0; k4 < 8; ++k4) {
            float zs[4][4];
#pragma unroll
            for (int i = 0; i < 4; ++i)
#pragma unroll
                for (int kk = 0; kk < 4; ++kk)
                    zs[i][kk] = zrow[(tr * 4 + i) * 33 + k4 * 4 + kk];
#pragma unroll
            for (int j = 0; j < 8; ++j) {
                float4 wv = *(const float4*)&wrow[(tc * 8 + j) * 32 + k4 * 4];
#pragma unroll
                for (int i = 0; i < 4; ++i)
                    y[i][j] = fmaf(zs[i][3], wv.w,
                              fmaf(zs[i][2], wv.z,
                              fmaf(zs[i][1], wv.y,
                              fmaf(zs[i][0], wv.x, y[i][j]))));
            }
        }
    }
#pragma unroll
    for (int j = 0; j < 8; ++j) {
        float b = b_in[tc * 8 + j];
#pragma unroll
        for (int i = 0; i < 4; ++i) y[i][j] += b;
    }
    __syncthreads();
#pragma unroll
    for (int i = 0; i < 4; ++i) {
        float s = 0.f;
#pragma unroll
        for (int j = 0; j < 8; ++j) s += y[i][j] * y[i][j];
        red[(tr * 4 + i) * 9 + tc] = s;
    }
    __syncthreads();
    float nrm[4];
#pragma unroll
    for (int i = 0; i < 4; ++i) {
        float t = 0.f;
#pragma unroll
        for (int t8 = 0; t8 < 8; ++t8) t += red[(tr * 4 + i) * 9 + t8];
        nrm[i] = sqrtf(t);
    }
    float q[4][8];
#pragma unroll
    for (int i = 0; i < 4; ++i)
#pragma unroll
        for (int j = 0; j < 8; ++j) q[i][j] = y[i][j] / nrm[i];
    // store transposed fp32: zqT[c][rb + tr*4 .. +3]
#pragma unroll
    for (int j = 0; j < 8; ++j) {
        int c = tc * 8 + j;
        float4 o = make_float4(q[0][j], q[1][j], q[2][j], q[3][j]);
        *(float4*)&zqT[(size_t)c * N + rb + tr * 4] = o;
    }
    // store row-major bf16 hi/lo: zqh/zql[row][64]
#pragma unroll
    for (int i = 0; i < 4; ++i) {
        unsigned short h[8], l[8];
#pragma unroll
        for (int j = 0; j < 8; ++j) {
            h[j] = f2bf(q[i][j]);
            l[j] = f2bf(q[i][j] - bf2f(h[j]));
        }
        uint4 hv, lv;
        hv.x = (unsigned)h[0] | ((unsigned)h[1] << 16);
        hv.y = (unsigned)h[2] | ((unsigned)h[3] << 16);
        hv.z = (unsigned)h[4] | ((unsigned)h[5] << 16);
        hv.w = (unsigned)h[6] | ((unsigned)h[7] << 16);
        lv.x = (unsigned)l[0] | ((unsigned)l[1] << 16);
        lv.y = (unsigned)l[2] | ((unsigned)l[3] << 16);
        lv.z = (unsigned)l[4] | ((unsigned)l[5] << 16);
        lv.w = (unsigned)l[6] | ((unsigned)l[7] << 16);
        size_t ro = (size_t)(rb + tr * 4 + i) * 64 + tc * 8;
        *(uint4*)&zqh[ro] = hv;
        *(uint4*)&zql[ro] = lv;
    }
}

// ---------------- K3: split-bf16 MFMA distance + top-2 argmin ----------------
// block = 256 thr = 4 waves; block covers 64 rows (wave: 16 rows = 1 m-tile)
// grid = N/64 = 512 -> 2 blocks/CU, 2 waves/SIMD (was 1: latency fully exposed)
__global__ __launch_bounds__(256) void k3_argmin_mfma(
    const unsigned short* __restrict__ zqh, const unsigned short* __restrict__ zql,
    const unsigned short* __restrict__ cnh, const unsigned short* __restrict__ cnl,
    const float* __restrict__ cc,
    int* __restrict__ idx_ws, float* __restrict__ idx_out,
    int* __restrict__ qn, int* __restrict__ qlist) {
    __shared__ unsigned short lfrag[8 * 4 * 64 * 8];   // [nt][f][lane][8] = 32 KB
    __shared__ float lcc[128];
    int tid = threadIdx.x;
    int w = tid >> 6, lane = tid & 63;
    int col = lane & 15, quad = lane >> 4;
    int rb = blockIdx.x * 64;
    int wrow = rb + w * 16;

    // A-frags (direct from global, once): A[m=lane&15][k=quad*8+j]
    short8 ah[2], al[2];
#pragma unroll
    for (int kf = 0; kf < 2; ++kf) {
        size_t off = (size_t)(wrow + col) * 64 + kf * 32 + quad * 8;
        ah[kf] = *(const short8*)&zqh[off];
        al[kf] = *(const short8*)&zql[off];
    }

    float d1[4], d2[4]; int i1[4], i2[4];
#pragma unroll
    for (int s = 0; s < 4; ++s) { d1[s] = 3.4e38f; d2[s] = 3.4e38f; i1[s] = 0; i2[s] = 0; }

    // staging role: quad-chunk fastest for 64B-contiguous global reads
    int sq = tid & 3, scol = (tid >> 2) & 15, sf = tid >> 6;   // sf: 0=hi k0,1=hi k1,2=lo k0,3=lo k1
    const unsigned short* ssrc = (sf & 2) ? cnl : cnh;
    int skf = sf & 1;

    for (int pt = 0; pt < P; pt += 128) {
        __syncthreads();
#pragma unroll
        for (int nt = 0; nt < 8; ++nt) {
            int p = pt + nt * 16 + scol;
            uint4 dv = *(const uint4*)&ssrc[(size_t)p * 64 + skf * 32 + sq * 8];
            *(uint4*)&lfrag[(((nt * 4 + sf) * 64) + sq * 16 + scol) * 8] = dv;
        }
        if (tid < 128) lcc[tid] = cc[pt + tid];
        __syncthreads();
#pragma unroll 2
        for (int nt = 0; nt < 8; ++nt) {
            short8 bh0 = *(const short8*)&lfrag[((nt * 4 + 0) * 64 + lane) * 8];
            short8 bh1 = *(const short8*)&lfrag[((nt * 4 + 1) * 64 + lane) * 8];
            short8 bl0 = *(const short8*)&lfrag[((nt * 4 + 2) * 64 + lane) * 8];
            short8 bl1 = *(const short8*)&lfrag[((nt * 4 + 3) * 64 + lane) * 8];
            float ccv = lcc[nt * 16 + col];
            int p = pt + nt * 16 + col;
            f32x4 acc = {0.f, 0.f, 0.f, 0.f};
            acc = __builtin_amdgcn_mfma_f32_16x16x32_bf16(ah[0], bh0, acc, 0, 0, 0);
            acc = __builtin_amdgcn_mfma_f32_16x16x32_bf16(ah[1], bh1, acc, 0, 0, 0);
            acc = __builtin_amdgcn_mfma_f32_16x16x32_bf16(ah[0], bl0, acc, 0, 0, 0);
            acc = __builtin_amdgcn_mfma_f32_16x16x32_bf16(ah[1], bl1, acc, 0, 0, 0);
            acc = __builtin_amdgcn_mfma_f32_16x16x32_bf16(al[0], bh0, acc, 0, 0, 0);
            acc = __builtin_amdgcn_mfma_f32_16x16x32_bf16(al[1], bh1, acc, 0, 0, 0);
#pragma unroll
            for (int s = 0; s < 4; ++s) {
                float d = fmaf(acc[s], -2.0f, ccv);   // ssq row-const: dropped (argmin invariant)
                bool lt1 = d < d1[s];
                bool lt2 = d < d2[s];
                float nd2 = lt1 ? d1[s] : (lt2 ? d : d2[s]);
                int   ni2 = lt1 ? i1[s] : (lt2 ? p : i2[s]);
                d1[s] = lt1 ? d : d1[s];
                i1[s] = lt1 ? p : i1[s];
                d2[s] = nd2; i2[s] = ni2;
            }
        }
    }
    // merge top-2 across the 16 cols sharing each row (xor 1,2,4,8 stays in-quad)
#pragma unroll
    for (int s = 0; s < 4; ++s) {
        float a1 = d1[s], a2 = d2[s]; int ai1 = i1[s], ai2 = i2[s];
#pragma unroll
        for (int m = 1; m <= 8; m <<= 1) {
            float b1 = __shfl_xor(a1, m); int bi1 = __shfl_xor(ai1, m);
            float b2 = __shfl_xor(a2, m); int bi2 = __shfl_xor(ai2, m);
            bool bw = (b1 < a1) || (b1 == a1 && bi1 < ai1);
            float w1 = bw ? b1 : a1; int wi1 = bw ? bi1 : ai1;
            float l1 = bw ? a1 : b1; int li1 = bw ? ai1 : bi1;
            float w2 = l1; int wi2 = li1;
            if (a2 < w2 || (a2 == w2 && ai2 < wi2)) { w2 = a2; wi2 = ai2; }
            if (b2 < w2 || (b2 == w2 && bi2 < wi2)) { w2 = b2; wi2 = bi2; }
            a1 = w1; ai1 = wi1; a2 = w2; ai2 = wi2;
        }
        if (col == 0) {
            int row = wrow + quad * 4 + s;
            idx_ws[row] = ai1;
            idx_out[row] = (float)ai1;
            if (a2 - a1 < TAU) {            // near-tie: exact fp32 recheck
                int qi = atomicAdd(qn, 1);
                qlist[qi] = row;
            }
        }
    }
}

// ---------------- K3r: exact fp32 full-row argmin for flagged rows ----------------
// One queue entry per block; row cached in LDS (broadcast reads, no VGPR array,
// no spill — R2's zr[64]-in-registers spilled at VGPR=48 and ran 1888 us).
__global__ __launch_bounds__(256) void k3_recheck(
    const float* __restrict__ zqT, const float* __restrict__ cnT,
    const float* __restrict__ cc, const int* __restrict__ qn,
    const int* __restrict__ qlist, int* __restrict__ idx_ws, float* __restrict__ idx_out) {
    __shared__ float zrow[64];
    __shared__ float bv[4];
    __shared__ int   bi4[4];
    int tid = threadIdx.x, w = tid >> 6, lane = tid & 63;
    int nq = qn[0];
    for (int e = blockIdx.x; e < nq; e += gridDim.x) {
        int row = qlist[e];
        __syncthreads();    // protect zrow/bv from previous iteration readers
        if (tid < 64) zrow[tid] = zqT[(size_t)tid * N + row];
        __syncthreads();
        float best = 3.4e38f; int bp = 0;
        for (int pb = w * 2048; pb < (w + 1) * 2048; pb += 64) {
            int p = pb + lane;
            float a0 = 0.f, a1 = 0.f, a2 = 0.f, a3 = 0.f;
#pragma unroll
            for (int k = 0; k < 64; k += 4) {
                a0 = fmaf(zrow[k + 0], cnT[(size_t)(k + 0) * P + p], a0);
                a1 = fmaf(zrow[k + 1], cnT[(size_t)(k + 1) * P + p], a1);
                a2 = fmaf(zrow[k + 2], cnT[(size_t)(k + 2) * P + p], a2);
                a3 = fmaf(zrow[k + 3], cnT[(size_t)(k + 3) * P + p], a3);
            }
            float d = fmaf((a0 + a1) + (a2 + a3), -2.0f, cc[p]);
            if (d < best) { best = d; bp = p; }   // per-lane p ascending: strict < keeps first
        }
#pragma unroll
        for (int m = 1; m < 64; m <<= 1) {
            float ob = __shfl_xor(best, m); int op = __shfl_xor(bp, m);
            if (ob < best || (ob == best && op < bp)) { best = ob; bp = op; }
        }
        if (lane == 0) { bv[w] = best; bi4[w] = bp; }
        __syncthreads();
        if (tid == 0) {
            float b = bv[0]; int pi = bi4[0];
#pragma unroll
            for (int ww = 1; ww < 4; ++ww)
                if (bv[ww] < b || (bv[ww] == b && bi4[ww] < pi)) { b = bv[ww]; pi = bi4[ww]; }
            idx_ws[row] = pi; idx_out[row] = (float)pi;
        }
    }
}

// ---------------- K3b: gather codesT[k][r] = cnT[k][idx[r]] ----------------
__global__ __launch_bounds__(256) void k3b_gather(
    const float* __restrict__ cnT, const int* __restrict__ idx, float* __restrict__ codesT) {
    for (size_t i = (size_t)blockIdx.x * 256 + threadIdx.x; i < (size_t)C * N;
         i += (size_t)gridDim.x * 256) {
        int k = (int)(i >> 15);          // N = 2^15
        int r = (int)(i & (N - 1));
        codesT[i] = cnT[(size_t)k * P + idx[r]];
    }
}

// ---------------- K4: out = codes @ w_out^T + b_out ----------------
__global__ __launch_bounds__(256) void k4_out(
    const float* __restrict__ codesT, const float* __restrict__ w_out,
    const float* __restrict__ b_out, float* __restrict__ out) {
    __shared__ float cds[64 * 64];
    __shared__ float wo[64 * 65];
    int tid = threadIdx.x;
    int tx = tid & 15;
    int ty = tid >> 4;
    int rb = blockIdx.x * 64;

    for (int i = tid; i < 64 * 64; i += 256) {
        int k = i >> 6, r = i & 63;
        cds[k * 64 + r] = codesT[(size_t)k * N + rb + r];
    }
    for (int ft = 0; ft < F; ft += 64) {
        __syncthreads();
        for (int i = tid; i < 64 * 64; i += 256) {
            int k = i & 63, f = i >> 6;
            wo[k * 65 + f] = w_out[(size_t)(ft + f) * C + k];
        }
        __syncthreads();
        float acc[4][4];
#pragma unroll
        for (int i = 0; i < 4; ++i)
#pragma unroll
            for (int j = 0; j < 4; ++j) acc[i][j] = 0.f;
#pragma unroll 8
        for (int k = 0; k < 64; ++k) {
            float4 cf = *(const float4*)&cds[k * 64 + ty * 4];
            float cr[4] = {cf.x, cf.y, cf.z, cf.w};
            float wv[4];
#pragma unroll
            for (int j = 0; j < 4; ++j) wv[j] = wo[k * 65 + tx * 4 + j];
#pragma unroll
            for (int i = 0; i < 4; ++i)
#pragma unroll
                for (int j = 0; j < 4; ++j)
                    acc[i][j] = fmaf(cr[i], wv[j], acc[i][j]);
        }
#pragma unroll
        for (int i = 0; i < 4; ++i) {
            int r = rb + ty * 4 + i;
            float4 o;
            o.x = acc[i][0] + b_out[ft + tx * 4 + 0];
            o.y = acc[i][1] + b_out[ft + tx * 4 + 1];
            o.z = acc[i][2] + b_out[ft + tx * 4 + 2];
            o.w = acc[i][3] + b_out[ft + tx * 4 + 3];
            *(float4*)&out[(size_t)r * F + ft + tx * 4] = o;
        }
    }
}

// ---------------- K5: loss partial sums ----------------
__global__ __launch_bounds__(256) void k5_loss(
    const float* __restrict__ zqT, const float* __restrict__ codesT, float* __restrict__ acc) {
    float s = 0.f;
    for (size_t i = (size_t)blockIdx.x * 256 + threadIdx.x; i < (size_t)C * N;
         i += (size_t)gridDim.x * 256) {
        float d = zqT[i] - codesT[i];
        s = fmaf(d, d, s);
    }
#pragma unroll
    for (int off = 32; off > 0; off >>= 1) s += __shfl_xor(s, off);
    __shared__ float wsum[4];
    int lane = threadIdx.x & 63, wv = threadIdx.x >> 6;
    if (lane == 0) wsum[wv] = s;
    __syncthreads();
    if (threadIdx.x == 0) atomicAdd(acc, wsum[0] + wsum[1] + wsum[2] + wsum[3]);
}

// ---------------- K6: finalize loss ----------------
__global__ void k6_finalize(const float* __restrict__ acc, float* __restrict__ loss_out) {
    float m = acc[0] / (float)(C * N);
    loss_out[0] = 0.25f * m + m;   // BETA*mean + mean
}

extern "C" void kernel_launch(void* const* d_in, const int* in_sizes, int n_in,
                              void* d_out, int out_size, void* d_ws, size_t ws_size,
                              hipStream_t stream) {
    const float* z      = (const float*)d_in[0];
    const float* w_in   = (const float*)d_in[1];
    const float* b_in   = (const float*)d_in[2];
    const float* w_out  = (const float*)d_in[3];
    const float* b_out  = (const float*)d_in[4];
    const float* cb     = (const float*)d_in[5];
    float* out = (float*)d_out;
    float* ws  = (float*)d_ws;

    unsigned short* cnh = (unsigned short*)(ws + WS_CNH);
    unsigned short* cnl = (unsigned short*)(ws + WS_CNL);
    unsigned short* zqh = (unsigned short*)(ws + WS_ZQH);
    unsigned short* zql = (unsigned short*)(ws + WS_ZQL);

    hipMemsetAsync(ws + WS_QN, 0, 2 * sizeof(float), stream);   // qn + loss acc
    k1_norm_codebook<<<P / 256, 256, 0, stream>>>(cb, ws + WS_CNT, ws + WS_CC, cnh, cnl);
    k2_project<<<N / 128, 256, 0, stream>>>(z, w_in, b_in, ws + WS_ZQT, zqh, zql);
    k3_argmin_mfma<<<N / 64, 256, 0, stream>>>(zqh, zql, cnh, cnl, ws + WS_CC,
                                               (int*)(ws + WS_IDX), out + OUT_IDX_OFF,
                                               (int*)(ws + WS_QN), (int*)(ws + WS_QLIST));
    k3_recheck<<<512, 256, 0, stream>>>(ws + WS_ZQT, ws + WS_CNT, ws + WS_CC,
                                        (const int*)(ws + WS_QN), (const int*)(ws + WS_QLIST),
                                        (int*)(ws + WS_IDX), out + OUT_IDX_OFF);
    k3b_gather<<<2048, 256, 0, stream>>>(ws + WS_CNT, (const int*)(ws + WS_IDX), ws + WS_CODEST);
    k4_out<<<N / 64, 256, 0, stream>>>(ws + WS_CODEST, w_out, b_out, out);
    k5_loss<<<2048, 256, 0, stream>>>(ws + WS_ZQT, ws + WS_CODEST, ws + WS_ACC);
    k6_finalize<<<1, 1, 0, stream>>>(ws + WS_ACC, out + OUT_LOSS_OFF);
}